// Round 3
// baseline (139.222 us; speedup 1.0000x reference)
//
#include <hip/hip_runtime.h>
#include <hip/hip_bf16.h>

#define DMODEL 512
#define NHEADS 8
#define DFF 2048
#define NSEQ 2048
#define NROWS 4096

typedef __attribute__((ext_vector_type(8))) short   bf16x8;   // MFMA A/B frag
typedef __attribute__((ext_vector_type(4))) float   f32x4;    // MFMA C/D frag
typedef __attribute__((ext_vector_type(8))) unsigned short u16x8;

__device__ __forceinline__ unsigned short f2bf(float f) {
  union { float f; unsigned u; } v; v.f = f;
  unsigned r = v.u + 0x7fffu + ((v.u >> 16) & 1u);   // RNE
  return (unsigned short)(r >> 16);
}
__device__ __forceinline__ float bf2f(unsigned short u) {
  union { unsigned u; float f; } v; v.u = (unsigned)u << 16;
  return v.f;
}

#define GLL16(src, dst) \
  __builtin_amdgcn_global_load_lds((__attribute__((address_space(1))) const void*)(src), \
                                   (__attribute__((address_space(3))) void*)(dst), 16, 0, 0)

// ---------------------------------------------------------------------------
// LayerNorm: one wave per row of 512, bf16 output.
// ---------------------------------------------------------------------------
__global__ __launch_bounds__(64)
void ln_kernel(const float* __restrict__ x, const float* __restrict__ g,
               const float* __restrict__ b, unsigned short* __restrict__ out) {
  const int row = blockIdx.x;
  const int lane = threadIdx.x;
  const float* xr = x + (size_t)row * DMODEL + lane * 8;
  const float4 v0 = *(const float4*)(xr);
  const float4 v1 = *(const float4*)(xr + 4);
  float s  = v0.x + v0.y + v0.z + v0.w + v1.x + v1.y + v1.z + v1.w;
  float s2 = v0.x*v0.x + v0.y*v0.y + v0.z*v0.z + v0.w*v0.w
           + v1.x*v1.x + v1.y*v1.y + v1.z*v1.z + v1.w*v1.w;
  #pragma unroll
  for (int m = 1; m < 64; m <<= 1) {
    s  += __shfl_xor(s,  m);
    s2 += __shfl_xor(s2, m);
  }
  const float mu  = s * (1.0f / DMODEL);
  const float var = s2 * (1.0f / DMODEL) - mu * mu;
  const float rs  = rsqrtf(var + 1e-5f);
  const float4 g0 = *(const float4*)(g + lane * 8);
  const float4 g1 = *(const float4*)(g + lane * 8 + 4);
  const float4 b0 = *(const float4*)(b + lane * 8);
  const float4 b1 = *(const float4*)(b + lane * 8 + 4);
  u16x8 o;
  o[0] = f2bf((v0.x - mu) * rs * g0.x + b0.x);
  o[1] = f2bf((v0.y - mu) * rs * g0.y + b0.y);
  o[2] = f2bf((v0.z - mu) * rs * g0.z + b0.z);
  o[3] = f2bf((v0.w - mu) * rs * g0.w + b0.w);
  o[4] = f2bf((v1.x - mu) * rs * g1.x + b1.x);
  o[5] = f2bf((v1.y - mu) * rs * g1.y + b1.y);
  o[6] = f2bf((v1.z - mu) * rs * g1.z + b1.z);
  o[7] = f2bf((v1.w - mu) * rs * g1.w + b1.w);
  *(u16x8*)(out + (size_t)row * DMODEL + lane * 8) = o;
}

// ---------------------------------------------------------------------------
// Weight transpose + fp32->bf16: w[K,N] -> wT[N,K]
// ---------------------------------------------------------------------------
__global__ __launch_bounds__(256)
void wt_kernel(const float* __restrict__ w, unsigned short* __restrict__ wT,
               int K, int N) {
  __shared__ unsigned short t[32][33];
  const int n0 = blockIdx.x * 32, k0 = blockIdx.y * 32;
  const int tx = threadIdx.x, ty = threadIdx.y;
  #pragma unroll
  for (int i = 0; i < 4; ++i)
    t[ty + i * 8][tx] = f2bf(w[(size_t)(k0 + ty + i * 8) * N + n0 + tx]);
  __syncthreads();
  #pragma unroll
  for (int i = 0; i < 4; ++i)
    wT[(size_t)(n0 + ty + i * 8) * K + k0 + tx] = t[tx][ty + i * 8];
}

// ---------------------------------------------------------------------------
// bf16 MFMA GEMM: C[M,N] = A[M,LDA-rowstride] @ Bt[N,LDA]^T (+bias/res/gelu)
// Tile BM x 64, BK=64, 256 threads = 4 waves.
//   BM=64 : waves 2x2, each 32x32 (acc[2][2])
//   BM=128: waves 2x2, each 64x32 (acc[4][2])
// LDS layout [kchunk(8)][row(BM)][8 elems] -> conflict-free ds_read_b128
// (16 consecutive rows = 16 consecutive 16B slots) AND linear for
// global_load_lds (lane l stages row l of one kchunk column).
// MODE: 0=+bias(f32) 1=+bias+res(f32) 2=+bias+gelu(bf16) 3=+bias(bf16)
// ---------------------------------------------------------------------------
template<int MODE, int BM>
__global__ __launch_bounds__(256)
void gemm_bf16(const unsigned short* __restrict__ A,
               const unsigned short* __restrict__ Bt,
               const float* __restrict__ bias, const float* __restrict__ res,
               void* __restrict__ Cout, int M, int N, int LDA, int KL) {
  constexpr int MR = BM / 32;                 // A-frags per wave
  __shared__ unsigned short As[2][BM * 64];   // 8 kchunks * BM rows * 8
  __shared__ unsigned short Bs[2][64 * 64];

  const int tid = threadIdx.x;
  const int w = tid >> 6, l = tid & 63;
  const int gx = N >> 6;
  const int nxy = gx * (M / BM);
  int lin = blockIdx.x;
  lin = (lin & 7) * (nxy >> 3) + (lin >> 3);  // bijective XCD swizzle (nxy%8==0)
  const int bn = (lin % gx) << 6;
  const int bm = (lin / gx) * BM;
  const int wr = (w >> 1) * (BM >> 1);
  const int wc = (w & 1) * 32;
  const int lr = l & 15, kg = l >> 4;

  f32x4 acc[MR][2] = {};

  auto stage = [&](int buf, int k0) {
    #pragma unroll
    for (int i = 0; i < BM / 32; ++i) {        // 8*BM/256 reps
      const int s0 = i * 256 + w * 64;
      const int cc = s0 / BM;
      const int rb = s0 % BM;
      GLL16(A + (size_t)(bm + rb + l) * LDA + k0 + cc * 8,
            &As[buf][(cc * BM + rb) * 8]);
    }
    #pragma unroll
    for (int i = 0; i < 2; ++i) {
      const int cc = i * 4 + w;
      GLL16(Bt + (size_t)(bn + l) * LDA + k0 + cc * 8,
            &Bs[buf][cc * 512]);
    }
  };

  const int nt = KL >> 6;
  stage(0, 0);
  int cur = 0;
  for (int t = 0; t < nt; ++t) {
    __syncthreads();                          // buf[cur] staged & prior reads done
    if (t + 1 < nt) stage(cur ^ 1, (t + 1) << 6);
    #pragma unroll
    for (int ks = 0; ks < 2; ++ks) {
      const int cc = ks * 4 + kg;
      bf16x8 af[MR], bfv[2];
      #pragma unroll
      for (int mi = 0; mi < MR; ++mi)
        af[mi] = *(const bf16x8*)&As[cur][(cc * BM + wr + mi * 16 + lr) * 8];
      #pragma unroll
      for (int ni = 0; ni < 2; ++ni)
        bfv[ni] = *(const bf16x8*)&Bs[cur][(cc * 64 + wc + ni * 16 + lr) * 8];
      #pragma unroll
      for (int mi = 0; mi < MR; ++mi)
        #pragma unroll
        for (int ni = 0; ni < 2; ++ni)
          acc[mi][ni] = __builtin_amdgcn_mfma_f32_16x16x32_bf16(
              af[mi], bfv[ni], acc[mi][ni], 0, 0, 0);
    }
    cur ^= 1;
  }

  // epilogue: C/D layout col=lane&15, row=(lane>>4)*4+reg
  float* Cf = (float*)Cout;
  unsigned short* Cb = (unsigned short*)Cout;
  #pragma unroll
  for (int mi = 0; mi < MR; ++mi) {
    #pragma unroll
    for (int ni = 0; ni < 2; ++ni) {
      const int gcol = bn + wc + ni * 16 + lr;
      const int grow0 = bm + wr + mi * 16 + kg * 4;
      const float bv = bias[gcol];
      #pragma unroll
      for (int reg = 0; reg < 4; ++reg) {
        const int grow = grow0 + reg;
        float t = acc[mi][ni][reg] + bv;
        if (MODE == 1) t += res[(size_t)grow * N + gcol];
        if (MODE == 2) t = 0.5f * t * (1.0f + erff(t * 0.70710678118654752f));
        if (MODE >= 2) Cb[(size_t)grow * N + gcol] = f2bf(t);
        else           Cf[(size_t)grow * N + gcol] = t;
      }
    }
  }
}

// ---------------------------------------------------------------------------
// Sparse geometric attention, bf16 qkv input, bf16 output.
// qkv row layout: [3][8][64] bf16 -> q at 0, k at +512, v at +1024.
// ---------------------------------------------------------------------------
#define CAP 256
__global__ __launch_bounds__(64)
void attn_kernel(const unsigned short* __restrict__ qkv,
                 const int* __restrict__ pos, const int* __restrict__ lvl,
                 unsigned short* __restrict__ out) {
  const int r = blockIdx.x;
  const int i = r & (NSEQ - 1);
  const int base = r - i;
  const int lane = threadIdx.x;

  __shared__ int   s_idx[CAP];
  __shared__ int   s_cnt;
  __shared__ float s_sc[NHEADS][CAP];
  __shared__ float s_inv[NHEADS];

  if (lane == 0) s_cnt = 0;
  __syncthreads();

  const int li = lvl[r];
  const int px = pos[2 * r], py = pos[2 * r + 1];
  const int win = (li == 0) ? 512 : (li == 1 ? 64 : 16);
  const int jlo = max(i - win + 1, 0);
  const int jhi = min(i + win - 1, NSEQ - 1);

  for (int j = jlo + lane; j <= jhi; j += 64) {
    const int rj = base + j;
    bool m = (j == i);
    if (!m) {
      const int lj = lvl[rj];
      const int d = abs(px - pos[2 * rj]) + abs(py - pos[2 * rj + 1]);
      m = (lj == li) && (d <= 1);
    }
    if (m) {
      const int p = atomicAdd(&s_cnt, 1);
      if (p < CAP) s_idx[p] = j;
    }
  }
  __syncthreads();
  const int cnt = min(s_cnt, CAP);

  const u16x8 qv = *(const u16x8*)(qkv + (size_t)r * 1536 + lane * 8);
  float qf[8];
  #pragma unroll
  for (int e = 0; e < 8; ++e) qf[e] = bf2f(qv[e]);

  for (int jj = 0; jj < cnt; ++jj) {
    const int rj = base + s_idx[jj];
    const u16x8 kv = *(const u16x8*)(qkv + (size_t)rj * 1536 + 512 + lane * 8);
    float p = 0.0f;
    #pragma unroll
    for (int e = 0; e < 8; ++e) p = fmaf(qf[e], bf2f(kv[e]), p);
    p += __shfl_xor(p, 1);
    p += __shfl_xor(p, 2);
    p += __shfl_xor(p, 4);
    if ((lane & 7) == 0) s_sc[lane >> 3][jj] = p * 0.125f;  // 1/sqrt(64)
  }
  __syncthreads();

  if (lane < 8) {
    float mx = -1e30f;
    for (int jj = 0; jj < cnt; ++jj) mx = fmaxf(mx, s_sc[lane][jj]);
    float den = 0.0f;
    for (int jj = 0; jj < cnt; ++jj) {
      const float e = expf(s_sc[lane][jj] - mx);
      s_sc[lane][jj] = e;
      den += e;
    }
    s_inv[lane] = 1.0f / den;
  }
  __syncthreads();

  const int h = lane >> 3;
  float a[8] = {};
  for (int jj = 0; jj < cnt; ++jj) {
    const float pp = s_sc[h][jj];
    const u16x8 vv = *(const u16x8*)(qkv + (size_t)(base + s_idx[jj]) * 1536 + 1024 + lane * 8);
    #pragma unroll
    for (int e = 0; e < 8; ++e) a[e] = fmaf(pp, bf2f(vv[e]), a[e]);
  }
  const float inv = s_inv[h];
  u16x8 o;
  #pragma unroll
  for (int e = 0; e < 8; ++e) o[e] = f2bf(a[e] * inv);
  *(u16x8*)(out + (size_t)r * DMODEL + lane * 8) = o;
}

// ---------------------------------------------------------------------------
extern "C" void kernel_launch(void* const* d_in, const int* in_sizes, int n_in,
                              void* d_out, int out_size, void* d_ws, size_t ws_size,
                              hipStream_t stream) {
  const float* x            = (const float*)d_in[0];
  const int*   coords_pos   = (const int*)d_in[1];
  const int*   coords_level = (const int*)d_in[2];
  const float* w_qkv        = (const float*)d_in[3];
  const float* b_qkv        = (const float*)d_in[4];
  const float* w_out        = (const float*)d_in[5];
  const float* b_out        = (const float*)d_in[6];
  const float* w_ff1        = (const float*)d_in[7];
  const float* b_ff1        = (const float*)d_in[8];
  const float* w_ff2        = (const float*)d_in[9];
  const float* b_ff2        = (const float*)d_in[10];
  const float* ln1_g        = (const float*)d_in[11];
  const float* ln1_b        = (const float*)d_in[12];
  const float* ln2_g        = (const float*)d_in[13];
  const float* ln2_b        = (const float*)d_in[14];
  float* out = (float*)d_out;

  // workspace layout (bytes)
  char* ws = (char*)d_ws;
  unsigned short* qkv_bf = (unsigned short*)(ws);             // 12.58MB (region 16.78MB)
  unsigned short* h_bf   = (unsigned short*)(ws);             // 16.78MB, reuses qkv region
  float*          x1     = (float*)(ws + 16777216);           // 8388608
  unsigned short* xn_bf  = (unsigned short*)(ws + 25165824);  // 4194304
  unsigned short* at_bf  = (unsigned short*)(ws + 29360128);  // 4194304
  unsigned short* wqkvT  = (unsigned short*)(ws + 33554432);  // 1572864
  unsigned short* woutT  = (unsigned short*)(ws + 35127296);  // 524288
  unsigned short* wff1T  = (unsigned short*)(ws + 35651584);  // 2097152
  unsigned short* wff2T  = (unsigned short*)(ws + 37748736);  // 2097152

  // weight transpose + cast
  wt_kernel<<<dim3(1536/32, 512/32),  dim3(32,8), 0, stream>>>(w_qkv, wqkvT, 512, 1536);
  wt_kernel<<<dim3(512/32,  512/32),  dim3(32,8), 0, stream>>>(w_out, woutT, 512, 512);
  wt_kernel<<<dim3(2048/32, 512/32),  dim3(32,8), 0, stream>>>(w_ff1, wff1T, 512, 2048);
  wt_kernel<<<dim3(512/32,  2048/32), dim3(32,8), 0, stream>>>(w_ff2, wff2T, 2048, 512);

  // 1. LN1 -> bf16
  ln_kernel<<<NROWS, 64, 0, stream>>>(x, ln1_g, ln1_b, xn_bf);
  // 2. QKV projection -> bf16   (768 blocks, 3/CU)
  gemm_bf16<3, 128><<<(1536/64)*(NROWS/128), 256, 0, stream>>>(
      xn_bf, wqkvT, b_qkv, nullptr, qkv_bf, NROWS, 1536, DMODEL, DMODEL);
  // 3. sparse geometric attention -> bf16
  attn_kernel<<<NROWS, 64, 0, stream>>>(qkv_bf, coords_pos, coords_level, at_bf);
  // 4. out projection + residual(x) -> fp32 x1   (512 blocks, 2/CU)
  gemm_bf16<1, 64><<<(DMODEL/64)*(NROWS/64), 256, 0, stream>>>(
      at_bf, woutT, b_out, x, x1, NROWS, DMODEL, DMODEL, DMODEL);
  // 5. LN2 -> bf16
  ln_kernel<<<NROWS, 64, 0, stream>>>(x1, ln2_g, ln2_b, xn_bf);
  // 6. FF1 + GELU -> bf16   (1024 blocks)
  gemm_bf16<2, 128><<<(DFF/64)*(NROWS/128), 256, 0, stream>>>(
      xn_bf, wff1T, b_ff1, nullptr, h_bf, NROWS, DFF, DMODEL, DMODEL);
  // 7. FF2 + residual(x1) -> d_out   (512 blocks, 2/CU)
  gemm_bf16<1, 64><<<(DMODEL/64)*(NROWS/64), 256, 0, stream>>>(
      h_bf, wff2T, b_ff2, x1, out, NROWS, DMODEL, DFF, DFF);
}

// Round 4
// 132.476 us; speedup vs baseline: 1.0509x; 1.0509x over previous
//
#include <hip/hip_runtime.h>
#include <hip/hip_bf16.h>

#define DMODEL 512
#define NHEADS 8
#define DFF 2048
#define NSEQ 2048
#define NROWS 4096

typedef __attribute__((ext_vector_type(8))) short   bf16x8;   // MFMA A/B frag
typedef __attribute__((ext_vector_type(4))) float   f32x4;    // MFMA C/D frag
typedef __attribute__((ext_vector_type(8))) unsigned short u16x8;

__device__ __forceinline__ unsigned short f2bf(float f) {
  union { float f; unsigned u; } v; v.f = f;
  unsigned r = v.u + 0x7fffu + ((v.u >> 16) & 1u);   // RNE
  return (unsigned short)(r >> 16);
}
__device__ __forceinline__ float bf2f(unsigned short u) {
  union { unsigned u; float f; } v; v.u = (unsigned)u << 16;
  return v.f;
}

#define GLL16(src, dst) \
  __builtin_amdgcn_global_load_lds((__attribute__((address_space(1))) const void*)(src), \
                                   (__attribute__((address_space(3))) void*)(dst), 16, 0, 0)

// ---------------------------------------------------------------------------
// LayerNorm: one wave per row of 512, bf16 output.
// ---------------------------------------------------------------------------
__global__ __launch_bounds__(64)
void ln_kernel(const float* __restrict__ x, const float* __restrict__ g,
               const float* __restrict__ b, unsigned short* __restrict__ out) {
  const int row = blockIdx.x;
  const int lane = threadIdx.x;
  const float* xr = x + (size_t)row * DMODEL + lane * 8;
  const float4 v0 = *(const float4*)(xr);
  const float4 v1 = *(const float4*)(xr + 4);
  float s  = v0.x + v0.y + v0.z + v0.w + v1.x + v1.y + v1.z + v1.w;
  float s2 = v0.x*v0.x + v0.y*v0.y + v0.z*v0.z + v0.w*v0.w
           + v1.x*v1.x + v1.y*v1.y + v1.z*v1.z + v1.w*v1.w;
  #pragma unroll
  for (int m = 1; m < 64; m <<= 1) {
    s  += __shfl_xor(s,  m);
    s2 += __shfl_xor(s2, m);
  }
  const float mu  = s * (1.0f / DMODEL);
  const float var = s2 * (1.0f / DMODEL) - mu * mu;
  const float rs  = rsqrtf(var + 1e-5f);
  const float4 g0 = *(const float4*)(g + lane * 8);
  const float4 g1 = *(const float4*)(g + lane * 8 + 4);
  const float4 b0 = *(const float4*)(b + lane * 8);
  const float4 b1 = *(const float4*)(b + lane * 8 + 4);
  u16x8 o;
  o[0] = f2bf((v0.x - mu) * rs * g0.x + b0.x);
  o[1] = f2bf((v0.y - mu) * rs * g0.y + b0.y);
  o[2] = f2bf((v0.z - mu) * rs * g0.z + b0.z);
  o[3] = f2bf((v0.w - mu) * rs * g0.w + b0.w);
  o[4] = f2bf((v1.x - mu) * rs * g1.x + b1.x);
  o[5] = f2bf((v1.y - mu) * rs * g1.y + b1.y);
  o[6] = f2bf((v1.z - mu) * rs * g1.z + b1.z);
  o[7] = f2bf((v1.w - mu) * rs * g1.w + b1.w);
  *(u16x8*)(out + (size_t)row * DMODEL + lane * 8) = o;
}

// ---------------------------------------------------------------------------
// All 4 weight transposes in one launch. w[K,N] -> wT[N,K] bf16.
// tiles: w_qkv 768 | w_out 256 | w_ff1 1024 | w_ff2 1024  => 3072 blocks
// ---------------------------------------------------------------------------
__global__ __launch_bounds__(256)
void wt_all(const float* __restrict__ w0, unsigned short* __restrict__ t0,
            const float* __restrict__ w1, unsigned short* __restrict__ t1,
            const float* __restrict__ w2, unsigned short* __restrict__ t2,
            const float* __restrict__ w3, unsigned short* __restrict__ t3) {
  __shared__ unsigned short t[32][33];
  int bid = blockIdx.x;
  const float* w; unsigned short* wT; int K, N;
  if (bid < 768)       { w = w0; wT = t0; K = 512;  N = 1536; }
  else if (bid < 1024) { bid -= 768;  w = w1; wT = t1; K = 512;  N = 512; }
  else if (bid < 2048) { bid -= 1024; w = w2; wT = t2; K = 512;  N = 2048; }
  else                 { bid -= 2048; w = w3; wT = t3; K = 2048; N = 512; }
  const int ntx = N >> 5;
  const int n0 = (bid % ntx) * 32, k0 = (bid / ntx) * 32;
  const int tx = threadIdx.x, ty = threadIdx.y;
  #pragma unroll
  for (int i = 0; i < 4; ++i)
    t[ty + i * 8][tx] = f2bf(w[(size_t)(k0 + ty + i * 8) * N + n0 + tx]);
  __syncthreads();
  #pragma unroll
  for (int i = 0; i < 4; ++i)
    wT[(size_t)(n0 + ty + i * 8) * K + k0 + tx] = t[tx][ty + i * 8];
}

// ---------------------------------------------------------------------------
// bf16 MFMA GEMM, 3-deep counted-vmcnt pipeline.
// C[M,N] = A[M,LDA] @ Bt[N,LDA]^T (+bias/res/gelu)
// Tile BM x 64, BK=64, 256 threads = 4 waves (2x2), wave tile (BM/2)x32.
// LDS layout [kchunk(8)][row(BM)][8] -> conflict-free ds_read_b128 and linear
// for global_load_lds.
// Per iter: s_waitcnt vmcnt(PS) ; s_barrier ; stage(t+2) ; ds_read ; MFMA.
// MODE: 0=+bias(f32) 1=+bias+res(f32) 2=+bias+gelu(bf16) 3=+bias(bf16)
// ---------------------------------------------------------------------------
template<int MODE, int BM>
__global__ __launch_bounds__(256)
void gemm_bf16(const unsigned short* __restrict__ A,
               const unsigned short* __restrict__ Bt,
               const float* __restrict__ bias, const float* __restrict__ res,
               void* __restrict__ Cout, int M, int N, int LDA, int KL) {
  constexpr int MR = BM / 32;                 // A-frags per wave
  constexpr int PS = BM / 32 + 2;             // GLL instructions per wave per stage
  __shared__ unsigned short As[3][BM * 64];
  __shared__ unsigned short Bs[3][64 * 64];

  const int tid = threadIdx.x;
  const int w = tid >> 6, l = tid & 63;
  const int gx = N >> 6;
  const int nxy = gx * (M / BM);
  int lin = blockIdx.x;
  lin = (lin & 7) * (nxy >> 3) + (lin >> 3);  // bijective XCD swizzle (nxy%8==0)
  const int bn = (lin % gx) << 6;
  const int bm = (lin / gx) * BM;
  const int wr = (w >> 1) * (BM >> 1);
  const int wc = (w & 1) * 32;
  const int lr = l & 15, kg = l >> 4;

  f32x4 acc[MR][2] = {};

  auto stage = [&](int buf, int k0) {
    #pragma unroll
    for (int i = 0; i < BM / 32; ++i) {
      const int s0 = i * 256 + w * 64;
      const int cc = s0 / BM;
      const int rb = s0 % BM;
      GLL16(A + (size_t)(bm + rb + l) * LDA + k0 + cc * 8,
            &As[buf][(cc * BM + rb) * 8]);
    }
    #pragma unroll
    for (int i = 0; i < 2; ++i) {
      const int cc = i * 4 + w;
      GLL16(Bt + (size_t)(bn + l) * LDA + k0 + cc * 8,
            &Bs[buf][cc * 512]);
    }
  };

  const int nt = KL >> 6;
  stage(0, 0);
  stage(1, 64);
  for (int t = 0; t < nt; ++t) {
    // tile t guaranteed resident; tile t+1 may remain in flight
    asm volatile("s_waitcnt vmcnt(%0)" :: "n"(PS) : "memory");
    __builtin_amdgcn_sched_barrier(0);
    __builtin_amdgcn_s_barrier();            // raw: does NOT drain vmcnt
    if (t + 2 < nt) stage((t + 2) % 3, (t + 2) << 6);
    const int cur = t % 3;
    #pragma unroll
    for (int ks = 0; ks < 2; ++ks) {
      const int cc = ks * 4 + kg;
      bf16x8 af[MR], bfv[2];
      #pragma unroll
      for (int mi = 0; mi < MR; ++mi)
        af[mi] = *(const bf16x8*)&As[cur][(cc * BM + wr + mi * 16 + lr) * 8];
      #pragma unroll
      for (int ni = 0; ni < 2; ++ni)
        bfv[ni] = *(const bf16x8*)&Bs[cur][(cc * 64 + wc + ni * 16 + lr) * 8];
      __builtin_amdgcn_s_setprio(1);
      #pragma unroll
      for (int mi = 0; mi < MR; ++mi)
        #pragma unroll
        for (int ni = 0; ni < 2; ++ni)
          acc[mi][ni] = __builtin_amdgcn_mfma_f32_16x16x32_bf16(
              af[mi], bfv[ni], acc[mi][ni], 0, 0, 0);
      __builtin_amdgcn_s_setprio(0);
    }
  }

  // epilogue: C/D layout col=lane&15, row=(lane>>4)*4+reg
  float* Cf = (float*)Cout;
  unsigned short* Cb = (unsigned short*)Cout;
  #pragma unroll
  for (int mi = 0; mi < MR; ++mi) {
    #pragma unroll
    for (int ni = 0; ni < 2; ++ni) {
      const int gcol = bn + wc + ni * 16 + lr;
      const int grow0 = bm + wr + mi * 16 + kg * 4;
      const float bv = bias[gcol];
      #pragma unroll
      for (int reg = 0; reg < 4; ++reg) {
        const int grow = grow0 + reg;
        float t = acc[mi][ni][reg] + bv;
        if (MODE == 1) t += res[(size_t)grow * N + gcol];
        if (MODE == 2) t = 0.5f * t * (1.0f + erff(t * 0.70710678118654752f));
        if (MODE >= 2) Cb[(size_t)grow * N + gcol] = f2bf(t);
        else           Cf[(size_t)grow * N + gcol] = t;
      }
    }
  }
}

// ---------------------------------------------------------------------------
// Sparse geometric attention, bf16 qkv input, bf16 output.
// qkv row layout: [3][8][64] bf16 -> q at 0, k at +512, v at +1024.
// ---------------------------------------------------------------------------
#define CAP 256
__global__ __launch_bounds__(64)
void attn_kernel(const unsigned short* __restrict__ qkv,
                 const int* __restrict__ pos, const int* __restrict__ lvl,
                 unsigned short* __restrict__ out) {
  const int r = blockIdx.x;
  const int i = r & (NSEQ - 1);
  const int base = r - i;
  const int lane = threadIdx.x;

  __shared__ int   s_idx[CAP];
  __shared__ int   s_cnt;
  __shared__ float s_sc[NHEADS][CAP];
  __shared__ float s_inv[NHEADS];

  if (lane == 0) s_cnt = 0;
  __syncthreads();

  const int li = lvl[r];
  const int2 pq = *(const int2*)(pos + 2 * r);
  const int win = (li == 0) ? 512 : (li == 1 ? 64 : 16);
  const int jlo = max(i - win + 1, 0);
  const int jhi = min(i + win - 1, NSEQ - 1);

  for (int j = jlo + lane; j <= jhi; j += 64) {
    const int rj = base + j;
    bool m = (j == i);
    if (!m) {
      const int lj = lvl[rj];
      const int2 pj = *(const int2*)(pos + 2 * rj);
      const int d = abs(pq.x - pj.x) + abs(pq.y - pj.y);
      m = (lj == li) && (d <= 1);
    }
    if (m) {
      const int p = atomicAdd(&s_cnt, 1);
      if (p < CAP) s_idx[p] = j;
    }
  }
  __syncthreads();
  const int cnt = min(s_cnt, CAP);

  const u16x8 qv = *(const u16x8*)(qkv + (size_t)r * 1536 + lane * 8);
  float qf[8];
  #pragma unroll
  for (int e = 0; e < 8; ++e) qf[e] = bf2f(qv[e]);

  for (int jj = 0; jj < cnt; ++jj) {
    const int rj = base + s_idx[jj];
    const u16x8 kv = *(const u16x8*)(qkv + (size_t)rj * 1536 + 512 + lane * 8);
    float p = 0.0f;
    #pragma unroll
    for (int e = 0; e < 8; ++e) p = fmaf(qf[e], bf2f(kv[e]), p);
    p += __shfl_xor(p, 1);
    p += __shfl_xor(p, 2);
    p += __shfl_xor(p, 4);
    if ((lane & 7) == 0) s_sc[lane >> 3][jj] = p * 0.125f;  // 1/sqrt(64)
  }
  __syncthreads();

  if (lane < 8) {
    float mx = -1e30f;
    for (int jj = 0; jj < cnt; ++jj) mx = fmaxf(mx, s_sc[lane][jj]);
    float den = 0.0f;
    for (int jj = 0; jj < cnt; ++jj) {
      const float e = expf(s_sc[lane][jj] - mx);
      s_sc[lane][jj] = e;
      den += e;
    }
    s_inv[lane] = 1.0f / den;
  }
  __syncthreads();

  const int h = lane >> 3;
  float a[8] = {};
  for (int jj = 0; jj < cnt; ++jj) {
    const float pp = s_sc[h][jj];
    const u16x8 vv = *(const u16x8*)(qkv + (size_t)(base + s_idx[jj]) * 1536 + 1024 + lane * 8);
    #pragma unroll
    for (int e = 0; e < 8; ++e) a[e] = fmaf(pp, bf2f(vv[e]), a[e]);
  }
  const float inv = s_inv[h];
  u16x8 o;
  #pragma unroll
  for (int e = 0; e < 8; ++e) o[e] = f2bf(a[e] * inv);
  *(u16x8*)(out + (size_t)r * DMODEL + lane * 8) = o;
}

// ---------------------------------------------------------------------------
extern "C" void kernel_launch(void* const* d_in, const int* in_sizes, int n_in,
                              void* d_out, int out_size, void* d_ws, size_t ws_size,
                              hipStream_t stream) {
  const float* x            = (const float*)d_in[0];
  const int*   coords_pos   = (const int*)d_in[1];
  const int*   coords_level = (const int*)d_in[2];
  const float* w_qkv        = (const float*)d_in[3];
  const float* b_qkv        = (const float*)d_in[4];
  const float* w_out        = (const float*)d_in[5];
  const float* b_out        = (const float*)d_in[6];
  const float* w_ff1        = (const float*)d_in[7];
  const float* b_ff1        = (const float*)d_in[8];
  const float* w_ff2        = (const float*)d_in[9];
  const float* b_ff2        = (const float*)d_in[10];
  const float* ln1_g        = (const float*)d_in[11];
  const float* ln1_b        = (const float*)d_in[12];
  const float* ln2_g        = (const float*)d_in[13];
  const float* ln2_b        = (const float*)d_in[14];
  float* out = (float*)d_out;

  // workspace layout (bytes)
  char* ws = (char*)d_ws;
  unsigned short* qkv_bf = (unsigned short*)(ws);             // 12.58MB (region 16.78MB)
  unsigned short* h_bf   = (unsigned short*)(ws);             // 16.78MB, reuses qkv region
  float*          x1     = (float*)(ws + 16777216);           // 8388608
  unsigned short* xn_bf  = (unsigned short*)(ws + 25165824);  // 4194304
  unsigned short* at_bf  = (unsigned short*)(ws + 29360128);  // 4194304
  unsigned short* wqkvT  = (unsigned short*)(ws + 33554432);  // 1572864
  unsigned short* woutT  = (unsigned short*)(ws + 35127296);  // 524288
  unsigned short* wff1T  = (unsigned short*)(ws + 35651584);  // 2097152
  unsigned short* wff2T  = (unsigned short*)(ws + 37748736);  // 2097152

  // all weight transposes in one launch
  wt_all<<<3072, dim3(32, 8), 0, stream>>>(w_qkv, wqkvT, w_out, woutT,
                                           w_ff1, wff1T, w_ff2, wff2T);

  // 1. LN1 -> bf16
  ln_kernel<<<NROWS, 64, 0, stream>>>(x, ln1_g, ln1_b, xn_bf);
  // 2. QKV projection -> bf16   (768 blocks)
  gemm_bf16<3, 128><<<(1536/64)*(NROWS/128), 256, 0, stream>>>(
      xn_bf, wqkvT, b_qkv, nullptr, qkv_bf, NROWS, 1536, DMODEL, DMODEL);
  // 3. sparse geometric attention -> bf16
  attn_kernel<<<NROWS, 64, 0, stream>>>(qkv_bf, coords_pos, coords_level, at_bf);
  // 4. out projection + residual(x) -> fp32 x1   (512 blocks)
  gemm_bf16<1, 64><<<(DMODEL/64)*(NROWS/64), 256, 0, stream>>>(
      at_bf, woutT, b_out, x, x1, NROWS, DMODEL, DMODEL, DMODEL);
  // 5. LN2 -> bf16
  ln_kernel<<<NROWS, 64, 0, stream>>>(x1, ln2_g, ln2_b, xn_bf);
  // 6. FF1 + GELU -> bf16   (1024 blocks)
  gemm_bf16<2, 128><<<(DFF/64)*(NROWS/128), 256, 0, stream>>>(
      xn_bf, wff1T, b_ff1, nullptr, h_bf, NROWS, DFF, DMODEL, DMODEL);
  // 7. FF2 + residual(x1) -> d_out   (512 blocks)
  gemm_bf16<1, 64><<<(DMODEL/64)*(NROWS/64), 256, 0, stream>>>(
      h_bf, wff2T, b_ff2, x1, out, NROWS, DMODEL, DFF, DFF);
}

// Round 5
// 112.263 us; speedup vs baseline: 1.2401x; 1.1800x over previous
//
#include <hip/hip_runtime.h>
#include <hip/hip_bf16.h>

#define DMODEL 512
#define NHEADS 8
#define DFF 2048
#define NSEQ 2048
#define NROWS 4096

typedef __attribute__((ext_vector_type(8))) short   bf16x8;   // MFMA A/B frag
typedef __attribute__((ext_vector_type(4))) float   f32x4;    // MFMA C/D frag
typedef __attribute__((ext_vector_type(8))) unsigned short u16x8;

__device__ __forceinline__ unsigned short f2bf(float f) {
  union { float f; unsigned u; } v; v.f = f;
  unsigned r = v.u + 0x7fffu + ((v.u >> 16) & 1u);   // RNE
  return (unsigned short)(r >> 16);
}
__device__ __forceinline__ float bf2f(unsigned short u) {
  union { unsigned u; float f; } v; v.u = (unsigned)u << 16;
  return v.f;
}

#define GLL16(src, dst) \
  __builtin_amdgcn_global_load_lds((__attribute__((address_space(1))) const void*)(src), \
                                   (__attribute__((address_space(3))) void*)(dst), 16, 0, 0)

// ---------------------------------------------------------------------------
// LayerNorm: one wave per row of 512, bf16 output.
// ---------------------------------------------------------------------------
__global__ __launch_bounds__(64)
void ln_kernel(const float* __restrict__ x, const float* __restrict__ g,
               const float* __restrict__ b, unsigned short* __restrict__ out) {
  const int row = blockIdx.x;
  const int lane = threadIdx.x;
  const float* xr = x + (size_t)row * DMODEL + lane * 8;
  const float4 v0 = *(const float4*)(xr);
  const float4 v1 = *(const float4*)(xr + 4);
  float s  = v0.x + v0.y + v0.z + v0.w + v1.x + v1.y + v1.z + v1.w;
  float s2 = v0.x*v0.x + v0.y*v0.y + v0.z*v0.z + v0.w*v0.w
           + v1.x*v1.x + v1.y*v1.y + v1.z*v1.z + v1.w*v1.w;
  #pragma unroll
  for (int m = 1; m < 64; m <<= 1) {
    s  += __shfl_xor(s,  m);
    s2 += __shfl_xor(s2, m);
  }
  const float mu  = s * (1.0f / DMODEL);
  const float var = s2 * (1.0f / DMODEL) - mu * mu;
  const float rs  = rsqrtf(var + 1e-5f);
  const float4 g0 = *(const float4*)(g + lane * 8);
  const float4 g1 = *(const float4*)(g + lane * 8 + 4);
  const float4 b0 = *(const float4*)(b + lane * 8);
  const float4 b1 = *(const float4*)(b + lane * 8 + 4);
  u16x8 o;
  o[0] = f2bf((v0.x - mu) * rs * g0.x + b0.x);
  o[1] = f2bf((v0.y - mu) * rs * g0.y + b0.y);
  o[2] = f2bf((v0.z - mu) * rs * g0.z + b0.z);
  o[3] = f2bf((v0.w - mu) * rs * g0.w + b0.w);
  o[4] = f2bf((v1.x - mu) * rs * g1.x + b1.x);
  o[5] = f2bf((v1.y - mu) * rs * g1.y + b1.y);
  o[6] = f2bf((v1.z - mu) * rs * g1.z + b1.z);
  o[7] = f2bf((v1.w - mu) * rs * g1.w + b1.w);
  *(u16x8*)(out + (size_t)row * DMODEL + lane * 8) = o;
}

// ---------------------------------------------------------------------------
// All 4 weight transposes in one launch. w[K,N] -> wT[N,K] bf16.
// ---------------------------------------------------------------------------
__global__ __launch_bounds__(256)
void wt_all(const float* __restrict__ w0, unsigned short* __restrict__ t0,
            const float* __restrict__ w1, unsigned short* __restrict__ t1,
            const float* __restrict__ w2, unsigned short* __restrict__ t2,
            const float* __restrict__ w3, unsigned short* __restrict__ t3) {
  __shared__ unsigned short t[32][33];
  int bid = blockIdx.x;
  const float* w; unsigned short* wT; int K, N;
  if (bid < 768)       { w = w0; wT = t0; K = 512;  N = 1536; }
  else if (bid < 1024) { bid -= 768;  w = w1; wT = t1; K = 512;  N = 512; }
  else if (bid < 2048) { bid -= 1024; w = w2; wT = t2; K = 512;  N = 2048; }
  else                 { bid -= 2048; w = w3; wT = t3; K = 2048; N = 512; }
  const int ntx = N >> 5;
  const int n0 = (bid % ntx) * 32, k0 = (bid / ntx) * 32;
  const int tx = threadIdx.x, ty = threadIdx.y;
  #pragma unroll
  for (int i = 0; i < 4; ++i)
    t[ty + i * 8][tx] = f2bf(w[(size_t)(k0 + ty + i * 8) * N + n0 + tx]);
  __syncthreads();
  #pragma unroll
  for (int i = 0; i < 4; ++i)
    wT[(size_t)(n0 + ty + i * 8) * K + k0 + tx] = t[tx][ty + i * 8];
}

// ---------------------------------------------------------------------------
// bf16 MFMA GEMM, 3-deep counted-vmcnt pipeline, coalesced staging.
// C[M,N] = A[M,LDA] @ Bt[N,LDA]^T (+bias/res/gelu)
// Tile BM x 64, BK=64, 256 threads = 4 waves (2x2), wave tile (BM/2)x32.
// LDS layout: row-major [row][64] (128B rows). Staging chunk c -> row=c>>3,
// kc=c&7: each GLL instruction covers 8 rows x 128B contiguous (coalesced),
// and the LDS dest is linear (wave-uniform base + lane*16).
// Per iter: s_waitcnt vmcnt(N) ; s_barrier ; sched_barrier ; stage(t+2) ;
//           ds_read ; MFMA (setprio-wrapped).
// MODE: 0=+bias(f32) 1=+bias+res(f32) 2=+bias+gelu(bf16) 3=+bias(bf16)
// ---------------------------------------------------------------------------
template<int MODE, int BM>
__global__ __launch_bounds__(256)
void gemm_bf16(const unsigned short* __restrict__ A,
               const unsigned short* __restrict__ Bt,
               const float* __restrict__ bias, const float* __restrict__ res,
               void* __restrict__ Cout, int M, int N, int LDA, int KL) {
  constexpr int MR = BM / 32;                 // A-frags per wave
  constexpr int PS = BM / 32 + 2;             // GLL instrs per wave per stage
  __shared__ unsigned short As[3][BM * 64];
  __shared__ unsigned short Bs[3][64 * 64];

  const int tid = threadIdx.x;
  const int w = tid >> 6, l = tid & 63;
  const int gx = N >> 6;
  const int nxy = gx * (M / BM);
  int lin = blockIdx.x;
  lin = (lin & 7) * (nxy >> 3) + (lin >> 3);  // bijective XCD swizzle (nxy%8==0)
  const int bn = (lin % gx) << 6;
  const int bm = (lin / gx) * BM;
  const int wr = (w >> 1) * (BM >> 1);
  const int wc = (w & 1) * 32;
  const int lr = l & 15, kg = l >> 4;

  f32x4 acc[MR][2] = {};

  auto stage = [&](int buf, int k0) {
    #pragma unroll
    for (int i = 0; i < BM / 32; ++i) {       // 64 chunks (8 rows) per GLL
      const int g = i * 4 + w;
      const int c = g * 64 + l;
      const int row = c >> 3, kc = c & 7;
      GLL16(A + (size_t)(bm + row) * LDA + k0 + kc * 8, &As[buf][g * 512]);
    }
    #pragma unroll
    for (int i = 0; i < 2; ++i) {
      const int g = i * 4 + w;
      const int c = g * 64 + l;
      const int row = c >> 3, kc = c & 7;
      GLL16(Bt + (size_t)(bn + row) * LDA + k0 + kc * 8, &Bs[buf][g * 512]);
    }
  };

  const int nt = KL >> 6;
  stage(0, 0);
  stage(1, 64);
  for (int t = 0; t < nt; ++t) {
    // tile t must be resident; tile t+1 may stay in flight (except last iter)
    if (t + 1 < nt) {
      asm volatile("s_waitcnt vmcnt(%0)" :: "n"(PS) : "memory");
    } else {
      asm volatile("s_waitcnt vmcnt(0)" ::: "memory");
    }
    __builtin_amdgcn_sched_barrier(0);
    __builtin_amdgcn_s_barrier();            // raw: does NOT drain vmcnt
    __builtin_amdgcn_sched_barrier(0);       // keep ds_reads below the barrier
    if (t + 2 < nt) stage((t + 2) % 3, (t + 2) << 6);
    const int cur = t % 3;
    #pragma unroll
    for (int ks = 0; ks < 2; ++ks) {
      const int cc = ks * 4 + kg;
      bf16x8 af[MR], bfv[2];
      #pragma unroll
      for (int mi = 0; mi < MR; ++mi)
        af[mi] = *(const bf16x8*)&As[cur][(wr + mi * 16 + lr) * 64 + cc * 8];
      #pragma unroll
      for (int ni = 0; ni < 2; ++ni)
        bfv[ni] = *(const bf16x8*)&Bs[cur][(wc + ni * 16 + lr) * 64 + cc * 8];
      __builtin_amdgcn_s_setprio(1);
      #pragma unroll
      for (int mi = 0; mi < MR; ++mi)
        #pragma unroll
        for (int ni = 0; ni < 2; ++ni)
          acc[mi][ni] = __builtin_amdgcn_mfma_f32_16x16x32_bf16(
              af[mi], bfv[ni], acc[mi][ni], 0, 0, 0);
      __builtin_amdgcn_s_setprio(0);
    }
  }

  // epilogue: C/D layout col=lane&15, row=(lane>>4)*4+reg
  float* Cf = (float*)Cout;
  unsigned short* Cb = (unsigned short*)Cout;
  #pragma unroll
  for (int mi = 0; mi < MR; ++mi) {
    #pragma unroll
    for (int ni = 0; ni < 2; ++ni) {
      const int gcol = bn + wc + ni * 16 + lr;
      const int grow0 = bm + wr + mi * 16 + kg * 4;
      const float bv = bias[gcol];
      #pragma unroll
      for (int reg = 0; reg < 4; ++reg) {
        const int grow = grow0 + reg;
        float t = acc[mi][ni][reg] + bv;
        if (MODE == 1) t += res[(size_t)grow * N + gcol];
        if (MODE == 2) t = 0.5f * t * (1.0f + erff(t * 0.70710678118654752f));
        if (MODE >= 2) Cb[(size_t)grow * N + gcol] = f2bf(t);
        else           Cf[(size_t)grow * N + gcol] = t;
      }
    }
  }
}

// ---------------------------------------------------------------------------
// Sparse geometric attention, bf16 qkv input, bf16 output.
// qkv row layout: [3][8][64] bf16 -> q at 0, k at +512, v at +1024.
// ---------------------------------------------------------------------------
#define CAP 256
__global__ __launch_bounds__(64)
void attn_kernel(const unsigned short* __restrict__ qkv,
                 const int* __restrict__ pos, const int* __restrict__ lvl,
                 unsigned short* __restrict__ out) {
  const int r = blockIdx.x;
  const int i = r & (NSEQ - 1);
  const int base = r - i;
  const int lane = threadIdx.x;

  __shared__ int   s_idx[CAP];
  __shared__ int   s_cnt;
  __shared__ float s_sc[NHEADS][CAP];
  __shared__ float s_inv[NHEADS];

  if (lane == 0) s_cnt = 0;
  __syncthreads();

  const int li = lvl[r];
  const int2 pq = *(const int2*)(pos + 2 * r);
  const int win = (li == 0) ? 512 : (li == 1 ? 64 : 16);
  const int jlo = max(i - win + 1, 0);
  const int jhi = min(i + win - 1, NSEQ - 1);

  for (int j = jlo + lane; j <= jhi; j += 64) {
    const int rj = base + j;
    bool m = (j == i);
    if (!m) {
      const int lj = lvl[rj];
      const int2 pj = *(const int2*)(pos + 2 * rj);
      const int d = abs(pq.x - pj.x) + abs(pq.y - pj.y);
      m = (lj == li) && (d <= 1);
    }
    if (m) {
      const int p = atomicAdd(&s_cnt, 1);
      if (p < CAP) s_idx[p] = j;
    }
  }
  __syncthreads();
  const int cnt = min(s_cnt, CAP);

  const u16x8 qv = *(const u16x8*)(qkv + (size_t)r * 1536 + lane * 8);
  float qf[8];
  #pragma unroll
  for (int e = 0; e < 8; ++e) qf[e] = bf2f(qv[e]);

  for (int jj = 0; jj < cnt; ++jj) {
    const int rj = base + s_idx[jj];
    const u16x8 kv = *(const u16x8*)(qkv + (size_t)rj * 1536 + 512 + lane * 8);
    float p = 0.0f;
    #pragma unroll
    for (int e = 0; e < 8; ++e) p = fmaf(qf[e], bf2f(kv[e]), p);
    p += __shfl_xor(p, 1);
    p += __shfl_xor(p, 2);
    p += __shfl_xor(p, 4);
    if ((lane & 7) == 0) s_sc[lane >> 3][jj] = p * 0.125f;  // 1/sqrt(64)
  }
  __syncthreads();

  if (lane < 8) {
    float mx = -1e30f;
    for (int jj = 0; jj < cnt; ++jj) mx = fmaxf(mx, s_sc[lane][jj]);
    float den = 0.0f;
    for (int jj = 0; jj < cnt; ++jj) {
      const float e = expf(s_sc[lane][jj] - mx);
      s_sc[lane][jj] = e;
      den += e;
    }
    s_inv[lane] = 1.0f / den;
  }
  __syncthreads();

  const int h = lane >> 3;
  float a[8] = {};
  for (int jj = 0; jj < cnt; ++jj) {
    const float pp = s_sc[h][jj];
    const u16x8 vv = *(const u16x8*)(qkv + (size_t)(base + s_idx[jj]) * 1536 + 1024 + lane * 8);
    #pragma unroll
    for (int e = 0; e < 8; ++e) a[e] = fmaf(pp, bf2f(vv[e]), a[e]);
  }
  const float inv = s_inv[h];
  u16x8 o;
  #pragma unroll
  for (int e = 0; e < 8; ++e) o[e] = f2bf(a[e] * inv);
  *(u16x8*)(out + (size_t)r * DMODEL + lane * 8) = o;
}

// ---------------------------------------------------------------------------
extern "C" void kernel_launch(void* const* d_in, const int* in_sizes, int n_in,
                              void* d_out, int out_size, void* d_ws, size_t ws_size,
                              hipStream_t stream) {
  const float* x            = (const float*)d_in[0];
  const int*   coords_pos   = (const int*)d_in[1];
  const int*   coords_level = (const int*)d_in[2];
  const float* w_qkv        = (const float*)d_in[3];
  const float* b_qkv        = (const float*)d_in[4];
  const float* w_out        = (const float*)d_in[5];
  const float* b_out        = (const float*)d_in[6];
  const float* w_ff1        = (const float*)d_in[7];
  const float* b_ff1        = (const float*)d_in[8];
  const float* w_ff2        = (const float*)d_in[9];
  const float* b_ff2        = (const float*)d_in[10];
  const float* ln1_g        = (const float*)d_in[11];
  const float* ln1_b        = (const float*)d_in[12];
  const float* ln2_g        = (const float*)d_in[13];
  const float* ln2_b        = (const float*)d_in[14];
  float* out = (float*)d_out;

  // workspace layout (bytes)
  char* ws = (char*)d_ws;
  unsigned short* qkv_bf = (unsigned short*)(ws);             // 12.58MB (region 16.78MB)
  unsigned short* h_bf   = (unsigned short*)(ws);             // 16.78MB, reuses qkv region
  float*          x1     = (float*)(ws + 16777216);           // 8388608
  unsigned short* xn_bf  = (unsigned short*)(ws + 25165824);  // 4194304
  unsigned short* at_bf  = (unsigned short*)(ws + 29360128);  // 4194304
  unsigned short* wqkvT  = (unsigned short*)(ws + 33554432);  // 1572864
  unsigned short* woutT  = (unsigned short*)(ws + 35127296);  // 524288
  unsigned short* wff1T  = (unsigned short*)(ws + 35651584);  // 2097152
  unsigned short* wff2T  = (unsigned short*)(ws + 37748736);  // 2097152

  // all weight transposes in one launch
  wt_all<<<3072, dim3(32, 8), 0, stream>>>(w_qkv, wqkvT, w_out, woutT,
                                           w_ff1, wff1T, w_ff2, wff2T);

  // 1. LN1 -> bf16
  ln_kernel<<<NROWS, 64, 0, stream>>>(x, ln1_g, ln1_b, xn_bf);
  // 2. QKV projection -> bf16   (768 blocks, 2/CU)
  gemm_bf16<3, 128><<<(1536/64)*(NROWS/128), 256, 0, stream>>>(
      xn_bf, wqkvT, b_qkv, nullptr, qkv_bf, NROWS, 1536, DMODEL, DMODEL);
  // 3. sparse geometric attention -> bf16
  attn_kernel<<<NROWS, 64, 0, stream>>>(qkv_bf, coords_pos, coords_level, at_bf);
  // 4. out projection + residual(x) -> fp32 x1   (512 blocks, 3/CU)
  gemm_bf16<1, 64><<<(DMODEL/64)*(NROWS/64), 256, 0, stream>>>(
      at_bf, woutT, b_out, x, x1, NROWS, DMODEL, DMODEL, DMODEL);
  // 5. LN2 -> bf16
  ln_kernel<<<NROWS, 64, 0, stream>>>(x1, ln2_g, ln2_b, xn_bf);
  // 6. FF1 + GELU -> bf16   (1024 blocks)
  gemm_bf16<2, 128><<<(DFF/64)*(NROWS/128), 256, 0, stream>>>(
      xn_bf, wff1T, b_ff1, nullptr, h_bf, NROWS, DFF, DMODEL, DMODEL);
  // 7. FF2 + residual(x1) -> d_out   (512 blocks, 3/CU)
  gemm_bf16<1, 64><<<(DMODEL/64)*(NROWS/64), 256, 0, stream>>>(
      h_bf, wff2T, b_ff2, x1, out, NROWS, DMODEL, DFF, DFF);
}